// Round 1
// baseline (110.071 us; speedup 1.0000x reference)
//
#include <hip/hip_runtime.h>

// HMLoss: 4-region histogram-matching L1 loss (face/hair/eyeL/eyeR), H=W=2048.
// ws layout: [0,24576) u32 hist[24][256]  (0..11 = src region*3+chan, 12..23 = tar)
//            [24576,24584) double accum
//            [24584,24584+12288) int tables[12][256]

#define FACEA_BITS ((1u<<1)|(1u<<7)|(1u<<8)|(1u<<10)|(1u<<11)|(1u<<14))
#define FACEB_BITS ((1u<<1)|(1u<<7)|(1u<<8)|(1u<<10)|(1u<<14))
#define HAIR_BITS  (1u<<17)
#define EYEL_BITS  ((1u<<2)|(1u<<4))
#define EYER_BITS  ((1u<<3)|(1u<<5))

__device__ __forceinline__ float denorm255(float x) {
  float t = (x + 1.0f) * 0.5f;
  t = fminf(fmaxf(t, 0.0f), 1.0f);
  return t * 255.0f;
}

__device__ __forceinline__ int bin_of(float v) {
  int b = (int)floorf(v * (256.0f / 255.0f));
  b = b < 0 ? 0 : b;
  return b > 255 ? 255 : b;
}

__device__ __forceinline__ int regionA(unsigned bit) {
  if (bit & FACEA_BITS) return 0;
  if (bit & HAIR_BITS)  return 1;
  if (bit & EYEL_BITS)  return 2;
  if (bit & EYER_BITS)  return 3;
  return -1;
}
__device__ __forceinline__ int regionB(unsigned bit) {
  if (bit & FACEB_BITS) return 0;
  if (bit & HAIR_BITS)  return 1;
  if (bit & EYEL_BITS)  return 2;
  if (bit & EYER_BITS)  return 3;
  return -1;
}

__global__ __launch_bounds__(1024) void hist_kernel(
    const float* __restrict__ fake, const float* __restrict__ refb,
    const int* __restrict__ ma, const int* __restrict__ mb,
    unsigned* __restrict__ ghist, int npix) {
  __shared__ unsigned h[6144];
  for (int i = threadIdx.x; i < 6144; i += blockDim.x) h[i] = 0u;
  __syncthreads();

  const int nq = npix >> 2;
  const int stride = gridDim.x * blockDim.x;
  const float4* f0p = (const float4*)fake;
  const float4* f1p = (const float4*)(fake + npix);
  const float4* f2p = (const float4*)(fake + 2 * npix);
  const float4* r0p = (const float4*)refb;
  const float4* r1p = (const float4*)(refb + npix);
  const float4* r2p = (const float4*)(refb + 2 * npix);
  const int4* map = (const int4*)ma;
  const int4* mbp = (const int4*)mb;

  for (int q = blockIdx.x * blockDim.x + threadIdx.x; q < nq; q += stride) {
    int4 m4 = map[q];
    int4 b4 = mbp[q];
    float4 f0 = f0p[q], f1 = f1p[q], f2 = f2p[q];
    float4 r0 = r0p[q], r1 = r1p[q], r2 = r2p[q];
    int mm[4] = {m4.x, m4.y, m4.z, m4.w};
    int bb[4] = {b4.x, b4.y, b4.z, b4.w};
    float fa[3][4] = {{f0.x,f0.y,f0.z,f0.w},{f1.x,f1.y,f1.z,f1.w},{f2.x,f2.y,f2.z,f2.w}};
    float rr[3][4] = {{r0.x,r0.y,r0.z,r0.w},{r1.x,r1.y,r1.z,r1.w},{r2.x,r2.y,r2.z,r2.w}};
#pragma unroll
    for (int k = 0; k < 4; ++k) {
      int sreg = regionA(1u << (mm[k] & 31));
      if (sreg >= 0) {
#pragma unroll
        for (int c = 0; c < 3; ++c)
          atomicAdd(&h[sreg * 768 + c * 256 + bin_of(denorm255(fa[c][k]))], 1u);
      }
      int treg = regionB(1u << (bb[k] & 31));
      int fval = (treg == 0 ? 1 : 0) + ((mm[k] == 11) ? 1 : 0);
      if (fval > 0) {
        float fs = (float)fval;
#pragma unroll
        for (int c = 0; c < 3; ++c)
          atomicAdd(&h[3072 + c * 256 + bin_of(denorm255(rr[c][k]) * fs)], 1u);
      }
      if (treg >= 1) {
#pragma unroll
        for (int c = 0; c < 3; ++c)
          atomicAdd(&h[3072 + treg * 768 + c * 256 + bin_of(denorm255(rr[c][k]))], 1u);
      }
    }
  }
  __syncthreads();
  // flush with per-block rotation to spread global-atomic address contention
  int rot = (blockIdx.x % 96) * 64;
  for (int i = threadIdx.x; i < 6144; i += blockDim.x) {
    int j = i + rot; if (j >= 6144) j -= 6144;
    unsigned v = h[j];
    if (v) atomicAdd(&ghist[j], v);
  }
}

// One block per (region,channel) pair: build both CDFs (bit-faithful f32
// sequential cumsum of count/sum) then the transfer table.
__global__ __launch_bounds__(256) void cdf_table_kernel(
    const unsigned* __restrict__ ghist, int* __restrict__ tbl) {
  __shared__ float dcdf[256];
  __shared__ float acdf[256];
  int r = blockIdx.x;  // 0..11
  int t = threadIdx.x;
  if (t < 2) {
    const unsigned* hh = ghist + (t == 0 ? r * 256 : 3072 + r * 256);
    float s = 0.0f;
    for (int b = 0; b < 256; ++b) s += (float)hh[b];
    s = fmaxf(s, 1.0f);
    float run = 0.0f;
    float* dst = (t == 0) ? dcdf : acdf;
    for (int b = 0; b < 256; ++b) { run += (float)hh[b] / s; dst[b] = run; }
  }
  __syncthreads();
  int out;
  if (t == 0) out = 0;
  else if (t == 255) out = 255;
  else {
    float di = dcdf[t];
    out = t;
    for (int j = 1; j < 256; ++j) {
      if (di >= acdf[j - 1] && di <= acdf[j]) { out = j; break; }
    }
  }
  tbl[r * 256 + t] = out;
}

__global__ __launch_bounds__(256) void loss_kernel(
    const float* __restrict__ fake, const int* __restrict__ ma,
    const int* __restrict__ tbl, double* __restrict__ acc, int npix) {
  __shared__ int tl[3072];
  for (int i = threadIdx.x; i < 3072; i += blockDim.x) tl[i] = tbl[i];
  __syncthreads();

  float local = 0.0f;
  const int nq = npix >> 2;
  const int stride = gridDim.x * blockDim.x;
  const float4* f0p = (const float4*)fake;
  const float4* f1p = (const float4*)(fake + npix);
  const float4* f2p = (const float4*)(fake + 2 * npix);
  const int4* map = (const int4*)ma;

  for (int q = blockIdx.x * blockDim.x + threadIdx.x; q < nq; q += stride) {
    int4 m4 = map[q];
    int mm[4] = {m4.x, m4.y, m4.z, m4.w};
    float4 f0 = f0p[q], f1 = f1p[q], f2 = f2p[q];
    float fa[3][4] = {{f0.x,f0.y,f0.z,f0.w},{f1.x,f1.y,f1.z,f1.w},{f2.x,f2.y,f2.z,f2.w}};
#pragma unroll
    for (int k = 0; k < 4; ++k) {
      int sreg = regionA(1u << (mm[k] & 31));
      if (sreg >= 0) {
#pragma unroll
        for (int c = 0; c < 3; ++c) {
          float v = denorm255(fa[c][k]);
          int idx = (int)v;            // v in [0,255], trunc == floor
          idx = idx > 255 ? 255 : idx;
          int lk = tl[sreg * 768 + c * 256 + idx];
          local += fabsf(v - (float)lk);
        }
      }
    }
  }

  // wave reduce then block reduce
  for (int off = 32; off > 0; off >>= 1) local += __shfl_down(local, off, 64);
  __shared__ float wsum[16];
  int lane = threadIdx.x & 63, wid = threadIdx.x >> 6;
  if (lane == 0) wsum[wid] = local;
  __syncthreads();
  if (threadIdx.x == 0) {
    float s = 0.0f;
    int nw = (blockDim.x + 63) >> 6;
    for (int w = 0; w < nw; ++w) s += wsum[w];
    atomicAdd(acc, (double)s);
  }
}

__global__ void finalize_kernel(const double* __restrict__ acc,
                                float* __restrict__ out, int npix) {
  out[0] = (float)(acc[0] * (0.1 / (3.0 * (double)npix)));
}

extern "C" void kernel_launch(void* const* d_in, const int* in_sizes, int n_in,
                              void* d_out, int out_size, void* d_ws, size_t ws_size,
                              hipStream_t stream) {
  const float* fake = (const float*)d_in[0];
  const float* refb = (const float*)d_in[1];
  const int* ma = (const int*)d_in[2];
  const int* mb = (const int*)d_in[3];
  const int npix = in_sizes[2];  // H*W

  unsigned* ghist = (unsigned*)d_ws;                    // 6144 u32
  double* acc = (double*)((char*)d_ws + 24576);         // 8 B
  int* tbl = (int*)((char*)d_ws + 24584);               // 3072 int
  float* out = (float*)d_out;

  hipMemsetAsync(d_ws, 0, 24584, stream);               // zero hists + accum
  hist_kernel<<<512, 1024, 0, stream>>>(fake, refb, ma, mb, ghist, npix);
  cdf_table_kernel<<<12, 256, 0, stream>>>(ghist, tbl);
  loss_kernel<<<2048, 256, 0, stream>>>(fake, ma, tbl, acc, npix);
  finalize_kernel<<<1, 1, 0, stream>>>(acc, out, npix);
}